// Round 1
// baseline (904.364 us; speedup 1.0000x reference)
//
#include <hip/hip_runtime.h>
#include <math.h>

#define T_TOK 4096
#define H_DIM 1024
#define E_NUM 8
#define I_DIM 4096

typedef __attribute__((ext_vector_type(4))) float f32x4;
typedef __attribute__((ext_vector_type(8))) short bf16x8;

__device__ inline unsigned short f2bf(float f) {
  unsigned int u = __float_as_uint(f);
  u += 0x7fffu + ((u >> 16) & 1u);   // round-to-nearest-even (finite data only)
  return (unsigned short)(u >> 16);
}

__device__ inline void cvt_store4(unsigned short* dst, const float* src) {
  f32x4 v = *reinterpret_cast<const f32x4*>(src);
  ushort4 o;
  o.x = f2bf(v[0]); o.y = f2bf(v[1]); o.z = f2bf(v[2]); o.w = f2bf(v[3]);
  *reinterpret_cast<ushort4*>(dst) = o;
}

// ---------------- router: fp32 logits, exact top-2 + softmax ----------------
__global__ __launch_bounds__(64) void k_router(const float* __restrict__ x,
                                               const float* __restrict__ gw,
                                               int2* __restrict__ tokE,
                                               float2* __restrict__ tokP,
                                               int* __restrict__ counts) {
  const int t = blockIdx.x;
  const int l = threadIdx.x;
  const float* xr = x + (size_t)t * H_DIM;
  float acc[E_NUM];
#pragma unroll
  for (int e = 0; e < E_NUM; e++) acc[e] = 0.f;
  for (int h = l; h < H_DIM; h += 64) {
    float xv = xr[h];
#pragma unroll
    for (int e = 0; e < E_NUM; e++) acc[e] += xv * gw[e * H_DIM + h];
  }
#pragma unroll
  for (int e = 0; e < E_NUM; e++) {
#pragma unroll
    for (int off = 32; off > 0; off >>= 1) acc[e] += __shfl_xor(acc[e], off);
  }
  if (l == 0) {
    float v0 = -1e30f, v1 = -1e30f;
    int e0 = 0, e1 = 0;
#pragma unroll
    for (int e = 0; e < E_NUM; e++) {
      float v = acc[e];
      if (v > v0) { v1 = v0; e1 = e0; v0 = v; e0 = e; }
      else if (v > v1) { v1 = v; e1 = e; }
    }
    float ex = expf(v1 - v0);          // v1 <= v0
    float p0 = 1.f / (1.f + ex);
    float p1 = ex * p0;
    tokE[t] = make_int2(e0, e1);
    tokP[t] = make_float2(p0, p1);
    atomicAdd(&counts[e0], 1);
    atomicAdd(&counts[e1], 1);
  }
}

__global__ void k_offsets(const int* __restrict__ counts, int* __restrict__ offsets) {
  if (threadIdx.x == 0 && blockIdx.x == 0) {
    int s = 0;
    for (int e = 0; e < E_NUM; e++) { offsets[e] = s; s += counts[e]; }
    offsets[E_NUM] = s;
  }
}

__global__ __launch_bounds__(256) void k_scatter(const int2* __restrict__ tokE,
                                                 const float2* __restrict__ tokP,
                                                 const int* __restrict__ offsets,
                                                 int* __restrict__ cursor,
                                                 int* __restrict__ slot_tok,
                                                 float* __restrict__ slot_w) {
  int t = blockIdx.x * 256 + threadIdx.x;
  if (t >= T_TOK) return;
  int2 e = tokE[t];
  float2 p = tokP[t];
  int pos0 = atomicAdd(&cursor[e.x], 1);
  slot_tok[offsets[e.x] + pos0] = t;
  slot_w[offsets[e.x] + pos0] = p.x;
  int pos1 = atomicAdd(&cursor[e.y], 1);
  slot_tok[offsets[e.y] + pos1] = t;
  slot_w[offsets[e.y] + pos1] = p.y;
}

// ------------- pass 1: hidden = silu(Xe @ wg^T) * (Xe @ wu^T) --------------
// 128(tokens) x 128(I) tile, BK=32 over H. 4 waves, each 64x64, dual acc.
__global__ __launch_bounds__(256) void k_gateup(
    const float* __restrict__ x, const float* __restrict__ wg,
    const float* __restrict__ wu, const int* __restrict__ counts,
    const int* __restrict__ offsets, const int* __restrict__ slot_tok,
    unsigned short* __restrict__ hidden) {
  const int e = blockIdx.z;
  const int cnt = counts[e];
  const int m0 = blockIdx.y * 128;
  if (m0 >= cnt) return;
  const int n0 = blockIdx.x * 128;
  const int base = offsets[e];

  __shared__ unsigned short As[128 * 40];
  __shared__ unsigned short Bgs[128 * 40];
  __shared__ unsigned short Bus[128 * 40];

  const int tid = threadIdx.x;
  const int wave = tid >> 6;
  const int lane = tid & 63;
  const int wm = (wave >> 1) * 64;
  const int wn = (wave & 1) * 64;
  const int lr = lane & 15;
  const int lk = lane >> 4;

  const int r_sub = tid >> 3;        // 0..31
  const int kq = (tid & 7) * 4;      // 0..28

  const float* wge = wg + (size_t)e * I_DIM * H_DIM;
  const float* wue = wu + (size_t)e * I_DIM * H_DIM;

  const float* aptr[4];
  const float* bgptr[4];
  const float* buptr[4];
#pragma unroll
  for (int p = 0; p < 4; p++) {
    int row = p * 32 + r_sub;
    int gr = m0 + row;
    if (gr > cnt - 1) gr = cnt - 1;
    aptr[p] = x + (size_t)slot_tok[base + gr] * H_DIM + kq;
    bgptr[p] = wge + (size_t)(n0 + row) * H_DIM + kq;
    buptr[p] = wue + (size_t)(n0 + row) * H_DIM + kq;
  }

  f32x4 accg[4][4], accu[4][4];
#pragma unroll
  for (int i = 0; i < 4; i++)
#pragma unroll
    for (int j = 0; j < 4; j++) {
      accg[i][j] = (f32x4){0.f, 0.f, 0.f, 0.f};
      accu[i][j] = (f32x4){0.f, 0.f, 0.f, 0.f};
    }

  for (int k0 = 0; k0 < H_DIM; k0 += 32) {
#pragma unroll
    for (int p = 0; p < 4; p++) {
      int row = p * 32 + r_sub;
      cvt_store4(&As[row * 40 + kq], aptr[p] + k0);
      cvt_store4(&Bgs[row * 40 + kq], bgptr[p] + k0);
      cvt_store4(&Bus[row * 40 + kq], buptr[p] + k0);
    }
    __syncthreads();
    bf16x8 af[4];
#pragma unroll
    for (int mf = 0; mf < 4; mf++)
      af[mf] = *reinterpret_cast<const bf16x8*>(&As[(wm + mf * 16 + lr) * 40 + lk * 8]);
#pragma unroll
    for (int nf = 0; nf < 4; nf++) {
      bf16x8 bg = *reinterpret_cast<const bf16x8*>(&Bgs[(wn + nf * 16 + lr) * 40 + lk * 8]);
      bf16x8 bu = *reinterpret_cast<const bf16x8*>(&Bus[(wn + nf * 16 + lr) * 40 + lk * 8]);
#pragma unroll
      for (int mf = 0; mf < 4; mf++) {
        accg[mf][nf] = __builtin_amdgcn_mfma_f32_16x16x32_bf16(af[mf], bg, accg[mf][nf], 0, 0, 0);
        accu[mf][nf] = __builtin_amdgcn_mfma_f32_16x16x32_bf16(af[mf], bu, accu[mf][nf], 0, 0, 0);
      }
    }
    __syncthreads();
  }

  // epilogue: h = silu(g) * u, store bf16
#pragma unroll
  for (int mf = 0; mf < 4; mf++) {
#pragma unroll
    for (int j = 0; j < 4; j++) {
      int row = wm + mf * 16 + lk * 4 + j;
      if (m0 + row < cnt) {
        size_t hbase = (size_t)(base + m0 + row) * I_DIM;
#pragma unroll
        for (int nf = 0; nf < 4; nf++) {
          int col = n0 + wn + nf * 16 + lr;
          float g = accg[mf][nf][j];
          float u = accu[mf][nf][j];
          float h = g / (1.f + expf(-g)) * u;
          hidden[hbase + col] = f2bf(h);
        }
      }
    }
  }
}

// ------------- pass 2: out[t] += w * (hidden_row @ wd^T) -------------------
// 128(tokens) x 128(H) tile, BK=32 over I. atomicAdd into zeroed out.
__global__ __launch_bounds__(256) void k_down(
    const unsigned short* __restrict__ hidden, const float* __restrict__ wd,
    const int* __restrict__ counts, const int* __restrict__ offsets,
    const int* __restrict__ slot_tok, const float* __restrict__ slot_w,
    float* __restrict__ out) {
  const int e = blockIdx.z;
  const int cnt = counts[e];
  const int m0 = blockIdx.y * 128;
  if (m0 >= cnt) return;
  const int n0 = blockIdx.x * 128;
  const int base = offsets[e];

  __shared__ unsigned short As[128 * 40];
  __shared__ unsigned short Bs[128 * 40];

  const int tid = threadIdx.x;
  const int wave = tid >> 6;
  const int lane = tid & 63;
  const int wm = (wave >> 1) * 64;
  const int wn = (wave & 1) * 64;
  const int lr = lane & 15;
  const int lk = lane >> 4;

  const int r_sub = tid >> 3;
  const int kq = (tid & 7) * 4;

  const unsigned short* ap[4];
  const float* bp[4];
#pragma unroll
  for (int p = 0; p < 4; p++) {
    int row = p * 32 + r_sub;
    int gr = m0 + row;
    if (gr > cnt - 1) gr = cnt - 1;
    ap[p] = hidden + (size_t)(base + gr) * I_DIM + kq;
    bp[p] = wd + (size_t)e * H_DIM * I_DIM + (size_t)(n0 + row) * I_DIM + kq;
  }

  f32x4 acc[4][4];
#pragma unroll
  for (int i = 0; i < 4; i++)
#pragma unroll
    for (int j = 0; j < 4; j++) acc[i][j] = (f32x4){0.f, 0.f, 0.f, 0.f};

  for (int k0 = 0; k0 < I_DIM; k0 += 32) {
#pragma unroll
    for (int p = 0; p < 4; p++) {
      int row = p * 32 + r_sub;
      *reinterpret_cast<ushort4*>(&As[row * 40 + kq]) =
          *reinterpret_cast<const ushort4*>(ap[p] + k0);
      cvt_store4(&Bs[row * 40 + kq], bp[p] + k0);
    }
    __syncthreads();
    bf16x8 af[4];
#pragma unroll
    for (int mf = 0; mf < 4; mf++)
      af[mf] = *reinterpret_cast<const bf16x8*>(&As[(wm + mf * 16 + lr) * 40 + lk * 8]);
#pragma unroll
    for (int nf = 0; nf < 4; nf++) {
      bf16x8 bf = *reinterpret_cast<const bf16x8*>(&Bs[(wn + nf * 16 + lr) * 40 + lk * 8]);
#pragma unroll
      for (int mf = 0; mf < 4; mf++)
        acc[mf][nf] = __builtin_amdgcn_mfma_f32_16x16x32_bf16(af[mf], bf, acc[mf][nf], 0, 0, 0);
    }
    __syncthreads();
  }

#pragma unroll
  for (int mf = 0; mf < 4; mf++) {
#pragma unroll
    for (int j = 0; j < 4; j++) {
      int row = wm + mf * 16 + lk * 4 + j;
      if (m0 + row < cnt) {
        int slot = base + m0 + row;
        int t = slot_tok[slot];
        float w = slot_w[slot];
#pragma unroll
        for (int nf = 0; nf < 4; nf++) {
          int col = n0 + wn + nf * 16 + lr;
          atomicAdd(&out[(size_t)t * H_DIM + col], w * acc[mf][nf][j]);
        }
      }
    }
  }
}

extern "C" void kernel_launch(void* const* d_in, const int* in_sizes, int n_in,
                              void* d_out, int out_size, void* d_ws, size_t ws_size,
                              hipStream_t stream) {
  const float* x = (const float*)d_in[0];
  const float* gate_w = (const float*)d_in[1];
  const float* wg = (const float*)d_in[2];
  const float* wu = (const float*)d_in[3];
  const float* wd = (const float*)d_in[4];
  float* out = (float*)d_out;

  char* ws = (char*)d_ws;
  int* counts = (int*)(ws + 0);        // 32 B
  int* cursor = (int*)(ws + 64);       // 32 B
  int* offsets = (int*)(ws + 128);     // 36 B
  int2* tokE = (int2*)(ws + 256);                 // 32 KB
  float2* tokP = (float2*)(ws + 256 + 32768);     // 32 KB
  int* slot_tok = (int*)(ws + 256 + 65536);       // 32 KB
  float* slot_w = (float*)(ws + 256 + 98304);     // 32 KB
  unsigned short* hidden = (unsigned short*)(ws + 131328);  // 64 MiB bf16

  hipMemsetAsync(d_ws, 0, 256, stream);  // counts + cursor
  hipMemsetAsync(d_out, 0, (size_t)T_TOK * H_DIM * sizeof(float), stream);

  k_router<<<T_TOK, 64, 0, stream>>>(x, gate_w, tokE, tokP, counts);
  k_offsets<<<1, 64, 0, stream>>>(counts, offsets);
  k_scatter<<<T_TOK / 256, 256, 0, stream>>>(tokE, tokP, offsets, cursor, slot_tok, slot_w);
  k_gateup<<<dim3(I_DIM / 128, 32, E_NUM), 256, 0, stream>>>(
      x, wg, wu, counts, offsets, slot_tok, hidden);
  k_down<<<dim3(H_DIM / 128, 32, E_NUM), 256, 0, stream>>>(
      hidden, wd, counts, offsets, slot_tok, slot_w, out);
}

// Round 2
// 563.535 us; speedup vs baseline: 1.6048x; 1.6048x over previous
//
#include <hip/hip_runtime.h>
#include <math.h>

#define T_TOK 4096
#define H_DIM 1024
#define E_NUM 8
#define I_DIM 4096

typedef __attribute__((ext_vector_type(4))) float f32x4;
typedef __attribute__((ext_vector_type(8))) short bf16x8;

__device__ inline unsigned short f2bf(float f) {
  unsigned int u = __float_as_uint(f);
  u += 0x7fffu + ((u >> 16) & 1u);   // RNE (finite data only)
  return (unsigned short)(u >> 16);
}

__device__ inline void cvt_store4(unsigned short* dst, const float* src) {
  f32x4 v = *reinterpret_cast<const f32x4*>(src);
  ushort4 o;
  o.x = f2bf(v[0]); o.y = f2bf(v[1]); o.z = f2bf(v[2]); o.w = f2bf(v[3]);
  *reinterpret_cast<ushort4*>(dst) = o;
}

// async global->LDS, 16B per lane; LDS dest is wave-uniform base + lane*16
__device__ inline void gll16(const void* g, void* l) {
  __builtin_amdgcn_global_load_lds(
      (const __attribute__((address_space(1))) void*)g,
      (__attribute__((address_space(3))) void*)l, 16, 0, 0);
}

// ---------------- router: fp32 logits, exact top-2 + softmax ----------------
__global__ __launch_bounds__(64) void k_router(const float* __restrict__ x,
                                               const float* __restrict__ gw,
                                               int2* __restrict__ tokE,
                                               float2* __restrict__ tokP,
                                               int* __restrict__ counts) {
  const int t = blockIdx.x;
  const int l = threadIdx.x;
  const float* xr = x + (size_t)t * H_DIM;
  float acc[E_NUM];
#pragma unroll
  for (int e = 0; e < E_NUM; e++) acc[e] = 0.f;
  for (int h = l; h < H_DIM; h += 64) {
    float xv = xr[h];
#pragma unroll
    for (int e = 0; e < E_NUM; e++) acc[e] += xv * gw[e * H_DIM + h];
  }
#pragma unroll
  for (int e = 0; e < E_NUM; e++) {
#pragma unroll
    for (int off = 32; off > 0; off >>= 1) acc[e] += __shfl_xor(acc[e], off);
  }
  if (l == 0) {
    float v0 = -1e30f, v1 = -1e30f;
    int e0 = 0, e1 = 0;
#pragma unroll
    for (int e = 0; e < E_NUM; e++) {
      float v = acc[e];
      if (v > v0) { v1 = v0; e1 = e0; v0 = v; e0 = e; }
      else if (v > v1) { v1 = v; e1 = e; }
    }
    float ex = expf(v1 - v0);
    float p0 = 1.f / (1.f + ex);
    float p1 = ex * p0;
    tokE[t] = make_int2(e0, e1);
    tokP[t] = make_float2(p0, p1);
    atomicAdd(&counts[e0], 1);
    atomicAdd(&counts[e1], 1);
  }
}

__global__ void k_offsets(const int* __restrict__ counts, int* __restrict__ offsets) {
  if (threadIdx.x == 0 && blockIdx.x == 0) {
    int s = 0;
    for (int e = 0; e < E_NUM; e++) { offsets[e] = s; s += counts[e]; }
    offsets[E_NUM] = s;
  }
}

__global__ __launch_bounds__(256) void k_scatter(const int2* __restrict__ tokE,
                                                 const float2* __restrict__ tokP,
                                                 const int* __restrict__ offsets,
                                                 int* __restrict__ cursor,
                                                 int* __restrict__ slot_tok,
                                                 float* __restrict__ slot_w) {
  int t = blockIdx.x * 256 + threadIdx.x;
  if (t >= T_TOK) return;
  int2 e = tokE[t];
  float2 p = tokP[t];
  int pos0 = atomicAdd(&cursor[e.x], 1);
  slot_tok[offsets[e.x] + pos0] = t;
  slot_w[offsets[e.x] + pos0] = p.x;
  int pos1 = atomicAdd(&cursor[e.y], 1);
  slot_tok[offsets[e.y] + pos1] = t;
  slot_w[offsets[e.y] + pos1] = p.y;
}

// ---------------- fp32 -> bf16 bulk convert (memory-bound) ------------------
__global__ __launch_bounds__(256) void k_cvt(const float* __restrict__ src,
                                             unsigned short* __restrict__ dst,
                                             int n4) {
  int i = blockIdx.x * 256 + threadIdx.x;
  const int stride = gridDim.x * 256;
  for (; i < n4; i += stride) {
    f32x4 v = reinterpret_cast<const f32x4*>(src)[i];
    ushort4 o;
    o.x = f2bf(v[0]); o.y = f2bf(v[1]); o.z = f2bf(v[2]); o.w = f2bf(v[3]);
    reinterpret_cast<ushort4*>(dst)[i] = o;
  }
}

// ======================= FAST PATH (bf16 + global_load_lds) =================
// pass 1: hidden = silu(Xe @ wg^T) * (Xe @ wu^T); 128x128 tile, BK=64.
// LDS layout [128][64] bf16 linear; XOR swizzle (chunk ^= row&7) applied on
// the per-lane GLOBAL source and on the ds_read side (rule #21).
__global__ __launch_bounds__(256, 2) void k_gateup2(
    const unsigned short* __restrict__ xb, const unsigned short* __restrict__ wgb,
    const unsigned short* __restrict__ wub, const int* __restrict__ counts,
    const int* __restrict__ offsets, const int* __restrict__ slot_tok,
    unsigned short* __restrict__ hidden) {
  const int e = blockIdx.z;
  const int cnt = counts[e];
  const int m0 = blockIdx.y * 128;
  if (m0 >= cnt) return;
  const int n0 = blockIdx.x * 128;
  const int base = offsets[e];

  __shared__ unsigned short As[128 * 64];
  __shared__ unsigned short Bg[128 * 64];
  __shared__ unsigned short Bu[128 * 64];

  const int tid = threadIdx.x;
  const int wave = tid >> 6;
  const int lane = tid & 63;
  const int wm = (wave >> 1) * 64;
  const int wn = (wave & 1) * 64;
  const int lr = lane & 15;
  const int lk = lane >> 4;

  // staging geometry: each wave stages rows [wave*32, wave*32+32), 4 issues of
  // 8 rows; lane -> row = sr, 16B chunk = sc; source chunk pre-swizzled.
  const int sr = lane >> 3;            // 0..7
  const int sc = lane & 7;             // 0..7
  const int swz = ((sc ^ sr) << 3);    // element offset of swizzled chunk

  const size_t wbase = (size_t)e * I_DIM * H_DIM;
  const unsigned short* srcA[4];
  const unsigned short* srcBg[4];
  const unsigned short* srcBu[4];
  unsigned short* dstA[4];
  unsigned short* dstBg[4];
  unsigned short* dstBu[4];
#pragma unroll
  for (int i = 0; i < 4; i++) {
    int row = wave * 32 + i * 8 + sr;
    int gr = m0 + row; if (gr > cnt - 1) gr = cnt - 1;
    srcA[i]  = xb + (size_t)slot_tok[base + gr] * H_DIM + swz;
    srcBg[i] = wgb + wbase + (size_t)(n0 + row) * H_DIM + swz;
    srcBu[i] = wub + wbase + (size_t)(n0 + row) * H_DIM + swz;
    dstA[i]  = &As[(wave * 32 + i * 8) * 64];
    dstBg[i] = &Bg[(wave * 32 + i * 8) * 64];
    dstBu[i] = &Bu[(wave * 32 + i * 8) * 64];
  }

  f32x4 accg[4][4], accu[4][4];
#pragma unroll
  for (int i = 0; i < 4; i++)
#pragma unroll
    for (int j = 0; j < 4; j++) {
      accg[i][j] = (f32x4){0.f, 0.f, 0.f, 0.f};
      accu[i][j] = (f32x4){0.f, 0.f, 0.f, 0.f};
    }

  const int xorr = ((lr & 7) << 3);    // read-side XOR (elements)

  for (int k0 = 0; k0 < H_DIM; k0 += 64) {
#pragma unroll
    for (int i = 0; i < 4; i++) {
      gll16(srcA[i] + k0, dstA[i]);
      gll16(srcBg[i] + k0, dstBg[i]);
      gll16(srcBu[i] + k0, dstBu[i]);
    }
    __syncthreads();
#pragma unroll
    for (int kh = 0; kh < 2; kh++) {
      const int koff = (((kh * 4 + lk) << 3) ^ xorr);
      bf16x8 af[4];
#pragma unroll
      for (int mf = 0; mf < 4; mf++)
        af[mf] = *reinterpret_cast<const bf16x8*>(&As[(wm + mf * 16 + lr) * 64 + koff]);
#pragma unroll
      for (int nf = 0; nf < 4; nf++) {
        const int roff = (wn + nf * 16 + lr) * 64 + koff;
        bf16x8 bg = *reinterpret_cast<const bf16x8*>(&Bg[roff]);
        bf16x8 bu = *reinterpret_cast<const bf16x8*>(&Bu[roff]);
#pragma unroll
        for (int mf = 0; mf < 4; mf++) {
          accg[mf][nf] = __builtin_amdgcn_mfma_f32_16x16x32_bf16(af[mf], bg, accg[mf][nf], 0, 0, 0);
          accu[mf][nf] = __builtin_amdgcn_mfma_f32_16x16x32_bf16(af[mf], bu, accu[mf][nf], 0, 0, 0);
        }
      }
    }
    __syncthreads();
  }

#pragma unroll
  for (int mf = 0; mf < 4; mf++) {
#pragma unroll
    for (int j = 0; j < 4; j++) {
      int row = wm + mf * 16 + lk * 4 + j;
      if (m0 + row < cnt) {
        size_t hbase = (size_t)(base + m0 + row) * I_DIM;
#pragma unroll
        for (int nf = 0; nf < 4; nf++) {
          int col = n0 + wn + nf * 16 + lr;
          float g = accg[mf][nf][j];
          float u = accu[mf][nf][j];
          float h = g / (1.f + expf(-g)) * u;
          hidden[hbase + col] = f2bf(h);
        }
      }
    }
  }
}

// pass 2: out[t] += w * (hidden_row @ wd^T); 128x128 tile, BK=64 over I.
__global__ __launch_bounds__(256, 2) void k_down2(
    const unsigned short* __restrict__ hidden, const unsigned short* __restrict__ wdb,
    const int* __restrict__ counts, const int* __restrict__ offsets,
    const int* __restrict__ slot_tok, const float* __restrict__ slot_w,
    float* __restrict__ out) {
  const int e = blockIdx.z;
  const int cnt = counts[e];
  const int m0 = blockIdx.y * 128;
  if (m0 >= cnt) return;
  const int n0 = blockIdx.x * 128;
  const int base = offsets[e];

  __shared__ unsigned short As[128 * 64];
  __shared__ unsigned short Bs[128 * 64];

  const int tid = threadIdx.x;
  const int wave = tid >> 6;
  const int lane = tid & 63;
  const int wm = (wave >> 1) * 64;
  const int wn = (wave & 1) * 64;
  const int lr = lane & 15;
  const int lk = lane >> 4;

  const int sr = lane >> 3;
  const int sc = lane & 7;
  const int swz = ((sc ^ sr) << 3);

  const unsigned short* srcA[4];
  const unsigned short* srcB[4];
  unsigned short* dstA[4];
  unsigned short* dstB[4];
#pragma unroll
  for (int i = 0; i < 4; i++) {
    int row = wave * 32 + i * 8 + sr;
    int gr = m0 + row; if (gr > cnt - 1) gr = cnt - 1;
    srcA[i] = hidden + (size_t)(base + gr) * I_DIM + swz;
    srcB[i] = wdb + (size_t)e * H_DIM * I_DIM + (size_t)(n0 + row) * I_DIM + swz;
    dstA[i] = &As[(wave * 32 + i * 8) * 64];
    dstB[i] = &Bs[(wave * 32 + i * 8) * 64];
  }

  f32x4 acc[4][4];
#pragma unroll
  for (int i = 0; i < 4; i++)
#pragma unroll
    for (int j = 0; j < 4; j++) acc[i][j] = (f32x4){0.f, 0.f, 0.f, 0.f};

  const int xorr = ((lr & 7) << 3);

  for (int k0 = 0; k0 < I_DIM; k0 += 64) {
#pragma unroll
    for (int i = 0; i < 4; i++) {
      gll16(srcA[i] + k0, dstA[i]);
      gll16(srcB[i] + k0, dstB[i]);
    }
    __syncthreads();
#pragma unroll
    for (int kh = 0; kh < 2; kh++) {
      const int koff = (((kh * 4 + lk) << 3) ^ xorr);
      bf16x8 af[4];
#pragma unroll
      for (int mf = 0; mf < 4; mf++)
        af[mf] = *reinterpret_cast<const bf16x8*>(&As[(wm + mf * 16 + lr) * 64 + koff]);
#pragma unroll
      for (int nf = 0; nf < 4; nf++) {
        bf16x8 bf = *reinterpret_cast<const bf16x8*>(&Bs[(wn + nf * 16 + lr) * 64 + koff]);
#pragma unroll
        for (int mf = 0; mf < 4; mf++)
          acc[mf][nf] = __builtin_amdgcn_mfma_f32_16x16x32_bf16(af[mf], bf, acc[mf][nf], 0, 0, 0);
      }
    }
    __syncthreads();
  }

#pragma unroll
  for (int mf = 0; mf < 4; mf++) {
#pragma unroll
    for (int j = 0; j < 4; j++) {
      int row = wm + mf * 16 + lk * 4 + j;
      if (m0 + row < cnt) {
        int slot = base + m0 + row;
        int t = slot_tok[slot];
        float w = slot_w[slot];
#pragma unroll
        for (int nf = 0; nf < 4; nf++) {
          int col = n0 + wn + nf * 16 + lr;
          atomicAdd(&out[(size_t)t * H_DIM + col], w * acc[mf][nf][j]);
        }
      }
    }
  }
}

// ================= FALLBACK PATH (round-1, fp32 in-loop convert) ============
__global__ __launch_bounds__(256) void k_gateup_v1(
    const float* __restrict__ x, const float* __restrict__ wg,
    const float* __restrict__ wu, const int* __restrict__ counts,
    const int* __restrict__ offsets, const int* __restrict__ slot_tok,
    unsigned short* __restrict__ hidden) {
  const int e = blockIdx.z;
  const int cnt = counts[e];
  const int m0 = blockIdx.y * 128;
  if (m0 >= cnt) return;
  const int n0 = blockIdx.x * 128;
  const int base = offsets[e];

  __shared__ unsigned short As[128 * 40];
  __shared__ unsigned short Bgs[128 * 40];
  __shared__ unsigned short Bus[128 * 40];

  const int tid = threadIdx.x;
  const int wave = tid >> 6;
  const int lane = tid & 63;
  const int wm = (wave >> 1) * 64;
  const int wn = (wave & 1) * 64;
  const int lr = lane & 15;
  const int lk = lane >> 4;
  const int r_sub = tid >> 3;
  const int kq = (tid & 7) * 4;

  const float* wge = wg + (size_t)e * I_DIM * H_DIM;
  const float* wue = wu + (size_t)e * I_DIM * H_DIM;

  const float* aptr[4];
  const float* bgptr[4];
  const float* buptr[4];
#pragma unroll
  for (int p = 0; p < 4; p++) {
    int row = p * 32 + r_sub;
    int gr = m0 + row;
    if (gr > cnt - 1) gr = cnt - 1;
    aptr[p] = x + (size_t)slot_tok[base + gr] * H_DIM + kq;
    bgptr[p] = wge + (size_t)(n0 + row) * H_DIM + kq;
    buptr[p] = wue + (size_t)(n0 + row) * H_DIM + kq;
  }

  f32x4 accg[4][4], accu[4][4];
#pragma unroll
  for (int i = 0; i < 4; i++)
#pragma unroll
    for (int j = 0; j < 4; j++) {
      accg[i][j] = (f32x4){0.f, 0.f, 0.f, 0.f};
      accu[i][j] = (f32x4){0.f, 0.f, 0.f, 0.f};
    }

  for (int k0 = 0; k0 < H_DIM; k0 += 32) {
#pragma unroll
    for (int p = 0; p < 4; p++) {
      int row = p * 32 + r_sub;
      cvt_store4(&As[row * 40 + kq], aptr[p] + k0);
      cvt_store4(&Bgs[row * 40 + kq], bgptr[p] + k0);
      cvt_store4(&Bus[row * 40 + kq], buptr[p] + k0);
    }
    __syncthreads();
    bf16x8 af[4];
#pragma unroll
    for (int mf = 0; mf < 4; mf++)
      af[mf] = *reinterpret_cast<const bf16x8*>(&As[(wm + mf * 16 + lr) * 40 + lk * 8]);
#pragma unroll
    for (int nf = 0; nf < 4; nf++) {
      bf16x8 bg = *reinterpret_cast<const bf16x8*>(&Bgs[(wn + nf * 16 + lr) * 40 + lk * 8]);
      bf16x8 bu = *reinterpret_cast<const bf16x8*>(&Bus[(wn + nf * 16 + lr) * 40 + lk * 8]);
#pragma unroll
      for (int mf = 0; mf < 4; mf++) {
        accg[mf][nf] = __builtin_amdgcn_mfma_f32_16x16x32_bf16(af[mf], bg, accg[mf][nf], 0, 0, 0);
        accu[mf][nf] = __builtin_amdgcn_mfma_f32_16x16x32_bf16(af[mf], bu, accu[mf][nf], 0, 0, 0);
      }
    }
    __syncthreads();
  }

#pragma unroll
  for (int mf = 0; mf < 4; mf++) {
#pragma unroll
    for (int j = 0; j < 4; j++) {
      int row = wm + mf * 16 + lk * 4 + j;
      if (m0 + row < cnt) {
        size_t hbase = (size_t)(base + m0 + row) * I_DIM;
#pragma unroll
        for (int nf = 0; nf < 4; nf++) {
          int col = n0 + wn + nf * 16 + lr;
          float g = accg[mf][nf][j];
          float u = accu[mf][nf][j];
          float h = g / (1.f + expf(-g)) * u;
          hidden[hbase + col] = f2bf(h);
        }
      }
    }
  }
}

__global__ __launch_bounds__(256) void k_down_v1(
    const unsigned short* __restrict__ hidden, const float* __restrict__ wd,
    const int* __restrict__ counts, const int* __restrict__ offsets,
    const int* __restrict__ slot_tok, const float* __restrict__ slot_w,
    float* __restrict__ out) {
  const int e = blockIdx.z;
  const int cnt = counts[e];
  const int m0 = blockIdx.y * 128;
  if (m0 >= cnt) return;
  const int n0 = blockIdx.x * 128;
  const int base = offsets[e];

  __shared__ unsigned short As[128 * 40];
  __shared__ unsigned short Bs[128 * 40];

  const int tid = threadIdx.x;
  const int wave = tid >> 6;
  const int lane = tid & 63;
  const int wm = (wave >> 1) * 64;
  const int wn = (wave & 1) * 64;
  const int lr = lane & 15;
  const int lk = lane >> 4;
  const int r_sub = tid >> 3;
  const int kq = (tid & 7) * 4;

  const unsigned short* ap[4];
  const float* bp[4];
#pragma unroll
  for (int p = 0; p < 4; p++) {
    int row = p * 32 + r_sub;
    int gr = m0 + row;
    if (gr > cnt - 1) gr = cnt - 1;
    ap[p] = hidden + (size_t)(base + gr) * I_DIM + kq;
    bp[p] = wd + (size_t)e * H_DIM * I_DIM + (size_t)(n0 + row) * I_DIM + kq;
  }

  f32x4 acc[4][4];
#pragma unroll
  for (int i = 0; i < 4; i++)
#pragma unroll
    for (int j = 0; j < 4; j++) acc[i][j] = (f32x4){0.f, 0.f, 0.f, 0.f};

  for (int k0 = 0; k0 < I_DIM; k0 += 32) {
#pragma unroll
    for (int p = 0; p < 4; p++) {
      int row = p * 32 + r_sub;
      *reinterpret_cast<ushort4*>(&As[row * 40 + kq]) =
          *reinterpret_cast<const ushort4*>(ap[p] + k0);
      cvt_store4(&Bs[row * 40 + kq], bp[p] + k0);
    }
    __syncthreads();
    bf16x8 af[4];
#pragma unroll
    for (int mf = 0; mf < 4; mf++)
      af[mf] = *reinterpret_cast<const bf16x8*>(&As[(wm + mf * 16 + lr) * 40 + lk * 8]);
#pragma unroll
    for (int nf = 0; nf < 4; nf++) {
      bf16x8 bf = *reinterpret_cast<const bf16x8*>(&Bs[(wn + nf * 16 + lr) * 40 + lk * 8]);
#pragma unroll
      for (int mf = 0; mf < 4; mf++)
        acc[mf][nf] = __builtin_amdgcn_mfma_f32_16x16x32_bf16(af[mf], bf, acc[mf][nf], 0, 0, 0);
    }
    __syncthreads();
  }

#pragma unroll
  for (int mf = 0; mf < 4; mf++) {
#pragma unroll
    for (int j = 0; j < 4; j++) {
      int row = wm + mf * 16 + lk * 4 + j;
      if (m0 + row < cnt) {
        int slot = base + m0 + row;
        int t = slot_tok[slot];
        float w = slot_w[slot];
#pragma unroll
        for (int nf = 0; nf < 4; nf++) {
          int col = n0 + wn + nf * 16 + lr;
          atomicAdd(&out[(size_t)t * H_DIM + col], w * acc[mf][nf][j]);
        }
      }
    }
  }
}

extern "C" void kernel_launch(void* const* d_in, const int* in_sizes, int n_in,
                              void* d_out, int out_size, void* d_ws, size_t ws_size,
                              hipStream_t stream) {
  const float* x = (const float*)d_in[0];
  const float* gate_w = (const float*)d_in[1];
  const float* wg = (const float*)d_in[2];
  const float* wu = (const float*)d_in[3];
  const float* wd = (const float*)d_in[4];
  float* out = (float*)d_out;

  char* ws = (char*)d_ws;
  int* counts = (int*)(ws + 0);
  int* cursor = (int*)(ws + 64);
  int* offsets = (int*)(ws + 128);
  int2* tokE = (int2*)(ws + 256);
  float2* tokP = (float2*)(ws + 256 + 32768);
  int* slot_tok = (int*)(ws + 256 + 65536);
  float* slot_w = (float*)(ws + 256 + 98304);

  hipMemsetAsync(d_ws, 0, 256, stream);  // counts + cursor
  hipMemsetAsync(d_out, 0, (size_t)T_TOK * H_DIM * sizeof(float), stream);

  k_router<<<T_TOK, 64, 0, stream>>>(x, gate_w, tokE, tokP, counts);
  k_offsets<<<1, 64, 0, stream>>>(counts, offsets);
  k_scatter<<<T_TOK / 256, 256, 0, stream>>>(tokE, tokP, offsets, cursor, slot_tok, slot_w);

  // fast-path workspace layout
  const size_t OFF_XB  = 262144;                       // 8 MiB bf16 x
  const size_t OFF_HID = OFF_XB + 8388608;             // 64 MiB bf16 hidden
  const size_t OFF_WG  = OFF_HID + 67108864;           // 64 MiB bf16 wg
  const size_t OFF_WU  = OFF_WG + 67108864;            // 64 MiB bf16 wu
  const size_t NEED    = OFF_WU + 67108864;            // wd aliases OFF_WG

  if (ws_size >= NEED) {
    unsigned short* xb  = (unsigned short*)(ws + OFF_XB);
    unsigned short* hid = (unsigned short*)(ws + OFF_HID);
    unsigned short* wgb = (unsigned short*)(ws + OFF_WG);
    unsigned short* wub = (unsigned short*)(ws + OFF_WU);
    unsigned short* wdb = wgb;  // aliased: converted after k_gateup2 is done with wgb

    k_cvt<<<2048, 256, 0, stream>>>(x, xb, T_TOK * H_DIM / 4);
    k_cvt<<<2048, 256, 0, stream>>>(wg, wgb, E_NUM * I_DIM * H_DIM / 4);
    k_cvt<<<2048, 256, 0, stream>>>(wu, wub, E_NUM * I_DIM * H_DIM / 4);
    k_gateup2<<<dim3(I_DIM / 128, 32, E_NUM), 256, 0, stream>>>(
        xb, wgb, wub, counts, offsets, slot_tok, hid);
    k_cvt<<<2048, 256, 0, stream>>>(wd, wdb, E_NUM * H_DIM * I_DIM / 4);
    k_down2<<<dim3(H_DIM / 128, 32, E_NUM), 256, 0, stream>>>(
        hid, wdb, counts, offsets, slot_tok, slot_w, out);
  } else {
    unsigned short* hid = (unsigned short*)(ws + 131328);
    k_gateup_v1<<<dim3(I_DIM / 128, 32, E_NUM), 256, 0, stream>>>(
        x, wg, wu, counts, offsets, slot_tok, hid);
    k_down_v1<<<dim3(H_DIM / 128, 32, E_NUM), 256, 0, stream>>>(
        hid, wd, counts, offsets, slot_tok, slot_w, out);
  }
}